// Round 7
// baseline (190.806 us; speedup 1.0000x reference)
//
#include <hip/hip_runtime.h>

typedef __attribute__((ext_vector_type(8))) _Float16 f16x8;
typedef __attribute__((ext_vector_type(4))) float   f32x4;

namespace {
constexpr int kB   = 8192;
constexpr int kTH  = 11;
constexpr int kTP  = 80;
constexpr int kM   = 16;    // batch rows per block (MFMA M)
constexpr int kStr = 72;    // H-plane row stride in fp16 units (144 B, 16B-aligned)
}

// 8 fp32 -> fp16x8 (round-to-nearest)
__device__ __forceinline__ f16x8 cvt8(const float* f) {
    f16x8 v;
#pragma unroll
    for (int j = 0; j < 8; ++j) v[j] = (_Float16)f[j];
    return v;
}

// B-fragment pair for column `col`: B[k][col] = W[col][k].
__device__ __forceinline__ void loadB1(const float* __restrict__ W, int col, int q,
                                       f16x8 (&Bf)[2]) {
#pragma unroll
    for (int c = 0; c < 2; ++c) {
        const float* src = W + col * 64 + c * 32 + q * 8;
        const float4 a = reinterpret_cast<const float4*>(src)[0];
        const float4 b = reinterpret_cast<const float4*>(src)[1];
        float f[8] = {a.x, a.y, a.z, a.w, b.x, b.y, b.z, b.w};
        Bf[c] = cvt8(f);
    }
}

// fc B-fragment (tile 0): cols p<2 real (fcW is 2x64), others zero.
__device__ __forceinline__ void loadBfc(const float* __restrict__ fcW, int p, int q,
                                        f16x8 (&Bf)[2]) {
#pragma unroll
    for (int c = 0; c < 2; ++c) {
        float f[8];
#pragma unroll
        for (int j = 0; j < 8; ++j)
            f[j] = (p < 2) ? fcW[p * 64 + c * 32 + q * 8 + j] : 0.f;
        Bf[c] = cvt8(f);
    }
}

// G = w0 (x) fcW[0] + w1 (x) fcW[1]  (rank-2 folded feedback matrix), own col
__device__ __forceinline__ void loadBG(const float* __restrict__ fcW, float w0, float w1,
                                       int q, f16x8 (&Bf)[2]) {
#pragma unroll
    for (int c = 0; c < 2; ++c) {
        float f[8];
#pragma unroll
        for (int j = 0; j < 8; ++j) {
            const int k = c * 32 + q * 8 + j;
            f[j] = w0 * fcW[k] + w1 * fcW[64 + k];
        }
        Bf[c] = cvt8(f);
    }
}

__device__ __forceinline__ f16x8 read_frag(const _Float16* plane, int off) {
    return *reinterpret_cast<const f16x8*>(plane + off);
}

__device__ __forceinline__ f32x4 mfma1(f16x8 a, f16x8 b, f32x4 acc) {
    return __builtin_amdgcn_mfma_f32_16x16x32_f16(a, b, acc, 0, 0, 0);
}

// tanh via raw v_exp/v_rcp: 1 - 2*rcp(2^(2*log2e*x)+1); saturates safely.
__device__ __forceinline__ float fast_tanh(float x) {
    const float e = __builtin_amdgcn_exp2f(x * 2.8853900817779268f);  // 2/ln2
    return fmaf(-2.0f, __builtin_amdgcn_rcpf(e + 1.0f), 1.0f);
}

// R16: ONE barrier per RNN step (93 total vs R9's 182).
// h1 stays col-split/published (4 waves x 16 cols); h2 is computed FULLY and
// REDUNDANTLY by every wave (16 MFMAs) into a private LDS plane and transposed
// in-wave (no barrier; R12-proven pattern). The h1->h2->h1 cycle then crosses
// waves only once per step. Occupancy stays at the 2048-wave maximum (2/SIMD);
// the redundant h2 issue lands in the measured 44% idle capacity.
__global__ __attribute__((amdgpu_waves_per_eu(2, 2))) __launch_bounds__(256)
void traj_rnn_kernel(
    const float* __restrict__ x,
    const float* __restrict__ eWih0, const float* __restrict__ eWhh0,
    const float* __restrict__ ebih0, const float* __restrict__ ebhh0,
    const float* __restrict__ eWih1, const float* __restrict__ eWhh1,
    const float* __restrict__ ebih1, const float* __restrict__ ebhh1,
    const float* __restrict__ dWih0, const float* __restrict__ dWhh0,
    const float* __restrict__ dbih0, const float* __restrict__ dbhh0,
    const float* __restrict__ dWih1, const float* __restrict__ dWhh1,
    const float* __restrict__ dbih1, const float* __restrict__ dbhh1,
    const float* __restrict__ fcW, const float* __restrict__ fcb,
    float* __restrict__ out)
{
    const int tid  = threadIdx.x;
    const int wv   = tid >> 6;
    const int lane = tid & 63;
    const int p    = lane & 15;
    const int q    = lane >> 4;
    const int col  = wv * 16 + p;       // own published h1 column
    const int r0   = blockIdx.x * kM;

    __shared__ __align__(16) _Float16 h1sh[2][kM * kStr];   // published h1, ping-pong
    __shared__ __align__(16) _Float16 h2pr[4][kM * kStr];   // per-wave private full h2
    __shared__ __align__(16) float xbuf[kM * kTH * 2];
    __shared__ __align__(16) float predbuf[kM * kTP * 2];

    for (int i = tid; i < kM * kTH * 2; i += 256)
        xbuf[i] = x[r0 * (kTH * 2) + i];

    _Float16* h2w  = h2pr[wv];
    const int aoff = p * kStr;

    const f16x8 Z = {0, 0, 0, 0, 0, 0, 0, 0};
    f16x8 H1f0 = Z, H1f1 = Z;     // published-h1 A-frags (row p, k = cols)
    f16x8 h2A0 = Z, h2A1 = Z;     // private full-h2 A-frags
    f32x4 a2p[4];                 // carried layer-2 partial (bias + Whh1.h2_old)

    // ---- encoder weights ----
    const float b0e = ebih0[col] + ebhh0[col];
    const float w0e = eWih0[col * 2 + 0], w1e = eWih0[col * 2 + 1];
    float b1e4[4];
    f16x8 B0e[2], B1e[8], B2e[8];
    loadB1(eWhh0, col, q, B0e);
    {
        f16x8 tmp[2];
#pragma unroll
        for (int n = 0; n < 4; ++n) {
            const int cn = p + 16 * n;
            b1e4[n] = ebih1[cn] + ebhh1[cn];
            loadB1(eWih1, cn, q, tmp); B1e[2 * n] = tmp[0]; B1e[2 * n + 1] = tmp[1];
            loadB1(eWhh1, cn, q, tmp); B2e[2 * n] = tmp[0]; B2e[2 * n + 1] = tmp[1];
        }
    }

    __syncthreads();   // xbuf visible

    // full h2 for one step: a2p + B1x^T.h1  -> tanh -> private write -> A-frags
    auto h2_step = [&](const f16x8* B1x) {
        f32x4 a0 = a2p[0], a1 = a2p[1], a2 = a2p[2], a3 = a2p[3];
        a0 = mfma1(H1f0, B1x[0], a0);  a1 = mfma1(H1f0, B1x[2], a1);
        a2 = mfma1(H1f0, B1x[4], a2);  a3 = mfma1(H1f0, B1x[6], a3);
        a0 = mfma1(H1f1, B1x[1], a0);  a1 = mfma1(H1f1, B1x[3], a1);
        a2 = mfma1(H1f1, B1x[5], a2);  a3 = mfma1(H1f1, B1x[7], a3);
#pragma unroll
        for (int r = 0; r < 4; ++r) {
            h2w[(4 * q + r) * kStr + p +  0] = (_Float16)fast_tanh(a0[r]);
            h2w[(4 * q + r) * kStr + p + 16] = (_Float16)fast_tanh(a1[r]);
            h2w[(4 * q + r) * kStr + p + 32] = (_Float16)fast_tanh(a2[r]);
            h2w[(4 * q + r) * kStr + p + 48] = (_Float16)fast_tanh(a3[r]);
        }
        h2A0 = read_frag(h2w, aoff + q * 8);          // in-wave transpose
        h2A1 = read_frag(h2w, aoff + 32 + q * 8);     // (lgkmcnt-ordered)
    };
    // next-step layer-2 partial: b1 + Whh1^T.h2(current)
    auto a2p_next = [&](const f16x8* B2x, const float* b1x) {
#pragma unroll
        for (int n = 0; n < 4; ++n) {
            f32x4 v = {b1x[n], b1x[n], b1x[n], b1x[n]};
            v = mfma1(h2A0, B2x[2 * n], v);
            v = mfma1(h2A1, B2x[2 * n + 1], v);
            a2p[n] = v;
        }
    };

    // ---- slot 0: publish h1e[0] (h1_prev = 0, h2_prev = 0) ----
    {
#pragma unroll
        for (int r = 0; r < 4; ++r) {
            const float2 xv = *reinterpret_cast<const float2*>(
                &xbuf[(4 * q + r) * (kTH * 2) + 0]);
            h1sh[0][(4 * q + r) * kStr + col] =
                (_Float16)fast_tanh(fmaf(w0e, xv.x, fmaf(w1e, xv.y, b0e)));
        }
#pragma unroll
        for (int n = 0; n < 4; ++n)
            a2p[n] = f32x4{b1e4[n], b1e4[n], b1e4[n], b1e4[n]};
        __syncthreads();
    }

    // ---- encoder slots t=1..10: publish h1e[t], compute h2e[t-1] ----
#pragma unroll 1
    for (int t = 1; t < kTH; ++t) {
        const _Float16* rpl = h1sh[(t - 1) & 1];
        _Float16*       wpl = h1sh[t & 1];
        H1f0 = read_frag(rpl, aoff + q * 8);
        H1f1 = read_frag(rpl, aoff + 32 + q * 8);
        f32x4 np = {b0e, b0e, b0e, b0e};
        np = mfma1(H1f0, B0e[0], np);
        np = mfma1(H1f1, B0e[1], np);
#pragma unroll
        for (int r = 0; r < 4; ++r) {
            const float2 xv = *reinterpret_cast<const float2*>(
                &xbuf[(4 * q + r) * (kTH * 2) + 2 * t]);
            wpl[(4 * q + r) * kStr + col] =
                (_Float16)fast_tanh(fmaf(w0e, xv.x, fmaf(w1e, xv.y, np[r])));
        }
        h2_step(B1e);            // h2e[t-1]
        a2p_next(B2e, b1e4);     // b1e + Whh1e.h2e[t-1]
        __syncthreads();
    }

    // ---- decoder weights ----
    const float b0d = dbih0[col] + dbhh0[col];
    const float w0d = dWih0[col * 2 + 0], w1d = dWih0[col * 2 + 1];
    const float fb0 = fcb[0], fb1 = fcb[1];
    const float b0p = b0d + w0d * fb0 + w1d * fb1;   // folded feedback bias
    const float fbp = (p == 0) ? fb0 : fb1;
    float b1d4[4];
    f16x8 B0d[2], BG[2], BF[2], B1d[8], B2d[8];
    loadB1(dWhh0, col, q, B0d);
    loadBG(fcW, w0d, w1d, q, BG);
    loadBfc(fcW, p, q, BF);
    {
        f16x8 tmp[2];
#pragma unroll
        for (int n = 0; n < 4; ++n) {
            const int cn = p + 16 * n;
            b1d4[n] = dbih1[cn] + dbhh1[cn];
            loadB1(dWih1, cn, q, tmp); B1d[2 * n] = tmp[0]; B1d[2 * n + 1] = tmp[1];
            loadB1(dWhh1, cn, q, tmp); B2d[2 * n] = tmp[0]; B2d[2 * n + 1] = tmp[1];
        }
    }

    // ---- transition slot (11): publish h1d[0]; compute h2e[10]; dec partial ----
    {
        const _Float16* rpl = h1sh[0];   // h1e[10] (slot 10 -> plane 0)
        _Float16*       wpl = h1sh[1];
        H1f0 = read_frag(rpl, aoff + q * 8);
        H1f1 = read_frag(rpl, aoff + 32 + q * 8);
        f32x4 np = {b0d, b0d, b0d, b0d};
        np = mfma1(H1f0, B0d[0], np);
        np = mfma1(H1f1, B0d[1], np);
#pragma unroll
        for (int r = 0; r < 4; ++r) {
            const float2 xv = *reinterpret_cast<const float2*>(
                &xbuf[(4 * q + r) * (kTH * 2) + 2 * (kTH - 1)]);
            wpl[(4 * q + r) * kStr + col] =
                (_Float16)fast_tanh(fmaf(w0d, xv.x, fmaf(w1d, xv.y, np[r])));
        }
        h2_step(B1e);            // h2e[10] = h2_T
        a2p_next(B2d, b1d4);     // b1d + Whh1d.h2_T
        __syncthreads();
    }

    // ---- decoder slots d=1..79: publish h1d[d]; compute h2d[d-1], pred[d-1] ----
#pragma unroll 1
    for (int d = 1; d < kTP; ++d) {
        const _Float16* rpl = h1sh[d & 1];           // h1d[d-1]
        _Float16*       wpl = h1sh[(d & 1) ^ 1];
        H1f0 = read_frag(rpl, aoff + q * 8);
        H1f1 = read_frag(rpl, aoff + 32 + q * 8);
        f32x4 nb = {0.f, 0.f, 0.f, 0.f};             // Whh0d.h1d[d-1] (early, off-chain)
        nb = mfma1(H1f0, B0d[0], nb);
        nb = mfma1(H1f1, B0d[1], nb);
        h2_step(B1d);                                // h2d[d-1] -> h2A frags
        f32x4 ng = {b0p, b0p, b0p, b0p};             // folded feedback G.h2d[d-1]
        ng = mfma1(h2A0, BG[0], ng);
        ng = mfma1(h2A1, BG[1], ng);
        f32x4 P = ng + nb;
#pragma unroll
        for (int r = 0; r < 4; ++r)
            wpl[(4 * q + r) * kStr + col] = (_Float16)fast_tanh(P[r]);
        // fc output pred[d-1] (all waves compute; wave 0 stores)
        f32x4 fcC = {0.f, 0.f, 0.f, 0.f};
        fcC = mfma1(h2A0, BF[0], fcC);
        fcC = mfma1(h2A1, BF[1], fcC);
        if (wv == 0 && p < 2) {
#pragma unroll
            for (int r = 0; r < 4; ++r)
                predbuf[((4 * q + r) * kTP + (d - 1)) * 2 + p] = fcC[r] + fbp;
        }
        a2p_next(B2d, b1d4);                         // b1d + Whh1d.h2d[d-1]
        __syncthreads();
    }

    // ---- epilogue: h2d[79] + pred[79] (no publish, no barrier needed) ----
    {
        const _Float16* rpl = h1sh[kTP & 1];         // h1d[79] (plane 0)
        H1f0 = read_frag(rpl, aoff + q * 8);
        H1f1 = read_frag(rpl, aoff + 32 + q * 8);
        h2_step(B1d);
        f32x4 fcC = {0.f, 0.f, 0.f, 0.f};
        fcC = mfma1(h2A0, BF[0], fcC);
        fcC = mfma1(h2A1, BF[1], fcC);
        if (wv == 0 && p < 2) {
#pragma unroll
            for (int r = 0; r < 4; ++r)
                predbuf[((4 * q + r) * kTP + (kTP - 1)) * 2 + p] = fcC[r] + fbp;
        }
    }

    // flush preds: block covers out[r0*kTP*2 .. (r0+16)*kTP*2), contiguous & aligned
    __syncthreads();
    {
        float4* dst = reinterpret_cast<float4*>(out + r0 * (kTP * 2));
        const float4* src = reinterpret_cast<const float4*>(predbuf);
        for (int i = tid; i < kM * kTP * 2 / 4; i += 256)
            dst[i] = src[i];
    }
}

extern "C" void kernel_launch(void* const* d_in, const int* in_sizes, int n_in,
                              void* d_out, int out_size, void* d_ws, size_t ws_size,
                              hipStream_t stream) {
    const float* x     = (const float*)d_in[0];
    const float* eWih0 = (const float*)d_in[1];
    const float* eWhh0 = (const float*)d_in[2];
    const float* ebih0 = (const float*)d_in[3];
    const float* ebhh0 = (const float*)d_in[4];
    const float* eWih1 = (const float*)d_in[5];
    const float* eWhh1 = (const float*)d_in[6];
    const float* ebih1 = (const float*)d_in[7];
    const float* ebhh1 = (const float*)d_in[8];
    const float* dWih0 = (const float*)d_in[9];
    const float* dWhh0 = (const float*)d_in[10];
    const float* dbih0 = (const float*)d_in[11];
    const float* dbhh0 = (const float*)d_in[12];
    const float* dWih1 = (const float*)d_in[13];
    const float* dWhh1 = (const float*)d_in[14];
    const float* dbih1 = (const float*)d_in[15];
    const float* dbhh1 = (const float*)d_in[16];
    const float* fcW   = (const float*)d_in[17];
    const float* fcb   = (const float*)d_in[18];
    float* out = (float*)d_out;

    dim3 grid(kB / kM);   // 512 blocks x 4 waves; 2 blocks/CU; 1 barrier/step
    dim3 block(256);
    traj_rnn_kernel<<<grid, block, 0, stream>>>(
        x, eWih0, eWhh0, ebih0, ebhh0, eWih1, eWhh1, ebih1, ebhh1,
        dWih0, dWhh0, dbih0, dbhh0, dWih1, dWhh1, dbih1, dbhh1,
        fcW, fcb, out);
}

// Round 8
// 169.165 us; speedup vs baseline: 1.1279x; 1.1279x over previous
//
#include <hip/hip_runtime.h>

typedef __attribute__((ext_vector_type(8))) _Float16 f16x8;
typedef __attribute__((ext_vector_type(4))) float   f32x4;

namespace {
constexpr int kB    = 8192;
constexpr int kTH   = 11;
constexpr int kTP   = 80;
constexpr int kM    = 8;     // REAL batch rows per block (halved vs R9)
constexpr int kMp   = 16;    // padded MFMA M (rows 8..15 are phantom)
constexpr int kStrH = 72;    // H-plane row stride in fp16 units (144 B: 16B-aligned)
}

// 8 fp32 -> fp16x8 (round-to-nearest)
__device__ __forceinline__ f16x8 cvt8(const float* f) {
    f16x8 v;
#pragma unroll
    for (int j = 0; j < 8; ++j) v[j] = (_Float16)f[j];
    return v;
}

// B-fragment (single fp16) for column `col`: B[k][col] = W[col][k].
__device__ __forceinline__ void loadB1(const float* __restrict__ W, int col, int q,
                                       f16x8 (&Bf)[2]) {
#pragma unroll
    for (int c = 0; c < 2; ++c) {
        const float* src = W + col * 64 + c * 32 + q * 8;
        const float4 a = reinterpret_cast<const float4*>(src)[0];
        const float4 b = reinterpret_cast<const float4*>(src)[1];
        float f[8] = {a.x, a.y, a.z, a.w, b.x, b.y, b.z, b.w};
        Bf[c] = cvt8(f);
    }
}

// fc B-fragment: only cols p<2 are real (fcW is 2x64); others zero.
__device__ __forceinline__ void loadBfc(const float* __restrict__ fcW, int p, int q,
                                        f16x8 (&Bf)[2]) {
#pragma unroll
    for (int c = 0; c < 2; ++c) {
        float f[8];
#pragma unroll
        for (int j = 0; j < 8; ++j)
            f[j] = (p < 2) ? fcW[p * 64 + c * 32 + q * 8 + j] : 0.f;
        Bf[c] = cvt8(f);
    }
}

// G = w0 (x) fcW[0] + w1 (x) fcW[1]  (rank-2 folded feedback matrix)
__device__ __forceinline__ void loadBG(const float* __restrict__ fcW, float w0, float w1,
                                       int q, f16x8 (&Bf)[2]) {
#pragma unroll
    for (int c = 0; c < 2; ++c) {
        float f[8];
#pragma unroll
        for (int j = 0; j < 8; ++j) {
            const int k = c * 32 + q * 8 + j;
            f[j] = w0 * fcW[k] + w1 * fcW[64 + k];
        }
        Bf[c] = cvt8(f);
    }
}

__device__ __forceinline__ f16x8 read_frag(const _Float16* plane, int off) {
    return *reinterpret_cast<const f16x8*>(plane + off);
}

// single-term accumulate: D += A*B (A = fp16 h, B = fp16 W)
__device__ __forceinline__ f32x4 mfma1(f16x8 a, f16x8 b, f32x4 acc) {
    return __builtin_amdgcn_mfma_f32_16x16x32_f16(a, b, acc, 0, 0, 0);
}

// tanh via raw v_exp/v_rcp: 1 - 2*rcp(2^(2*log2e*x)+1); saturates safely.
__device__ __forceinline__ float fast_tanh(float x) {
    const float e = __builtin_amdgcn_exp2f(x * 2.8853900817779268f);  // 2/ln2
    return fmaf(-2.0f, __builtin_amdgcn_rcpf(e + 1.0f), 1.0f);
}

// R17 = R9 schedule EXACTLY, but kM=8 real rows in a padded 16-row MFMA tile:
// 1024 blocks x 4 waves = 4096 waves = 4 waves/SIMD from 4 INDEPENDENT blocks
// (4 uncorrelated barrier domains per SIMD vs R9's 2 -> stall windows covered).
// Phantom rows 8..15 see zeroed x, stay bounded through tanh, are never
// flushed; real-row arithmetic is bit-identical to R9. MFMA work doubles per
// delivered row -- paid from the 82%-idle matrix pipe.
__global__ __attribute__((amdgpu_waves_per_eu(4, 4))) __launch_bounds__(256)
void traj_rnn_kernel(
    const float* __restrict__ x,
    const float* __restrict__ eWih0, const float* __restrict__ eWhh0,
    const float* __restrict__ ebih0, const float* __restrict__ ebhh0,
    const float* __restrict__ eWih1, const float* __restrict__ eWhh1,
    const float* __restrict__ ebih1, const float* __restrict__ ebhh1,
    const float* __restrict__ dWih0, const float* __restrict__ dWhh0,
    const float* __restrict__ dbih0, const float* __restrict__ dbhh0,
    const float* __restrict__ dWih1, const float* __restrict__ dWhh1,
    const float* __restrict__ dbih1, const float* __restrict__ dbhh1,
    const float* __restrict__ fcW, const float* __restrict__ fcb,
    float* __restrict__ out)
{
    const int tid  = threadIdx.x;
    const int wv   = tid >> 6;          // n-tile owned by this wave (0..3)
    const int lane = tid & 63;
    const int p    = lane & 15;         // A-m / C-col-within-tile
    const int q    = lane >> 4;         // k-quad / C row-quad
    const int col  = wv * 16 + p;       // this lane's hidden-unit column
    const int r0   = blockIdx.x * kM;

    __shared__ __align__(16) _Float16 Hhi1[kMp * kStrH];
    __shared__ __align__(16) _Float16 Hhi2[kMp * kStrH];
    __shared__ __align__(16) float xbuf[kMp * kTH * 2];      // rows 8..15 zeroed
    __shared__ __align__(16) float predbuf[kMp * kTP * 2];   // rows 8..15 never flushed

    for (int i = tid; i < kMp * kTH * 2; i += 256)
        xbuf[i] = (i < kM * kTH * 2) ? x[r0 * (kTH * 2) + i] : 0.f;

    f16x8 H1f[2], H2f[2];
#pragma unroll
    for (int c = 0; c < 2; ++c) {
        H1f[c] = f16x8{0, 0, 0, 0, 0, 0, 0, 0};
        H2f[c] = f16x8{0, 0, 0, 0, 0, 0, 0, 0};
    }
    __syncthreads();

    const int aoff = p * kStrH;  // A-fragment base for this lane's m-row

    // ================= encoder: 11 steps =================
    {
        const float b0 = ebih0[col] + ebhh0[col];
        const float b1 = ebih1[col] + ebhh1[col];
        const float w0 = eWih0[col * 2 + 0];
        const float w1 = eWih0[col * 2 + 1];
        f16x8 B0[2], B1[2], B2[2];
        loadB1(eWhh0, col, q, B0);   // Whh0
        loadB1(eWih1, col, q, B1);   // Wih1
        loadB1(eWhh1, col, q, B2);   // Whh1

        f32x4 P1 = {b0, b0, b0, b0};       // b0 + Whh0 . h1 (h1 = 0 initially)

#pragma unroll 1
        for (int t = 0; t < kTH; ++t) {
#pragma unroll
            for (int r = 0; r < 4; ++r) {
                const float2 xv = *reinterpret_cast<const float2*>(
                    &xbuf[(4 * q + r) * (kTH * 2) + 2 * t]);
                const float h1 = fast_tanh(fmaf(w0, xv.x, fmaf(w1, xv.y, P1[r])));
                Hhi1[(4 * q + r) * kStrH + col] = (_Float16)h1;
            }
            // layer-2 partial on OLD H2 (independent of h1') before the barrier
            f32x4 a2 = {b1, b1, b1, b1};
#pragma unroll
            for (int c = 0; c < 2; ++c)
                a2 = mfma1(H2f[c], B2[c], a2);
            __syncthreads();   // h1' visible

            // segment A->B: chain-critical a2 finish, produce h2'
#pragma unroll
            for (int c = 0; c < 2; ++c)
                H1f[c] = read_frag(Hhi1, aoff + c * 32 + q * 8);
#pragma unroll
            for (int c = 0; c < 2; ++c)
                a2 = mfma1(H1f[c], B1[c], a2);
#pragma unroll
            for (int r = 0; r < 4; ++r) {
                const float h2 = fast_tanh(a2[r]);
                Hhi2[(4 * q + r) * kStrH + col] = (_Float16)h2;
            }
            __syncthreads();   // h2' visible

            // segment B->A: next-P1 recurrent term (H1 frags still live)
#pragma unroll
            for (int c = 0; c < 2; ++c)
                H2f[c] = read_frag(Hhi2, aoff + c * 32 + q * 8);
            f32x4 np = {b0, b0, b0, b0};
#pragma unroll
            for (int c = 0; c < 2; ++c)
                np = mfma1(H1f[c], B0[c], np);
            P1 = np;
        }
    }

    // ================= decoder: 80 autoregressive steps =================
    {
        const float b0 = dbih0[col] + dbhh0[col];
        const float b1 = dbih1[col] + dbhh1[col];
        const float w0 = dWih0[col * 2 + 0];
        const float w1 = dWih0[col * 2 + 1];
        const float fb0 = fcb[0];
        const float fb1 = fcb[1];
        // folded bias: feedback constant term absorbed into layer-1 bias
        const float b0p = b0 + w0 * fb0 + w1 * fb1;
        const float fbp = (p == 0) ? fb0 : fb1;   // for LDS stash from p<2 lanes
        f16x8 B0[2], B1[2], B2[2], BF[2], BG[2];
        loadB1(dWhh0, col, q, B0);
        loadB1(dWih1, col, q, B1);
        loadB1(dWhh1, col, q, B2);
        loadBfc(fcW, p, q, BF);
        loadBG(fcW, w0, w1, q, BG);   // rank-2 folded feedback matrix

        // P1 for the FIRST decoder step: b0 + Whh0.h1_enc + w0*x_last0 + w1*x_last1
        f32x4 P1 = {b0, b0, b0, b0};
#pragma unroll
        for (int c = 0; c < 2; ++c)
            P1 = mfma1(H1f[c], B0[c], P1);
#pragma unroll
        for (int r = 0; r < 4; ++r) {
            const float2 xv = *reinterpret_cast<const float2*>(
                &xbuf[(4 * q + r) * (kTH * 2) + 2 * (kTH - 1)]);
            P1[r] = fmaf(w0, xv.x, fmaf(w1, xv.y, P1[r]));
        }

#pragma unroll 2
        for (int t = 0; t < kTP; ++t) {
            // layer 1: P1 is already complete (bias + recurrent + folded feedback)
#pragma unroll
            for (int r = 0; r < 4; ++r) {
                const float h1 = fast_tanh(P1[r]);
                Hhi1[(4 * q + r) * kStrH + col] = (_Float16)h1;
            }
            // layer-2 partial on OLD H2 before the barrier
            f32x4 a2 = {b1, b1, b1, b1};
#pragma unroll
            for (int c = 0; c < 2; ++c)
                a2 = mfma1(H2f[c], B2[c], a2);
            __syncthreads();   // h1' visible

            // segment A->B: chain-critical only — finish a2, produce h2'
#pragma unroll
            for (int c = 0; c < 2; ++c)
                H1f[c] = read_frag(Hhi1, aoff + c * 32 + q * 8);
#pragma unroll
            for (int c = 0; c < 2; ++c)
                a2 = mfma1(H1f[c], B1[c], a2);
#pragma unroll
            for (int r = 0; r < 4; ++r) {
                const float h2 = fast_tanh(a2[r]);
                Hhi2[(4 * q + r) * kStrH + col] = (_Float16)h2;
            }
            __syncthreads();   // h2' visible

            // segment B->A: next-P1 as TWO independent 2-chains (G.h2 || B0.h1),
            // merged with one vector add — shortens the np critical path.
#pragma unroll
            for (int c = 0; c < 2; ++c)
                H2f[c] = read_frag(Hhi2, aoff + c * 32 + q * 8);
            f32x4 ng = {b0p, b0p, b0p, b0p};
            f32x4 nb = {0.f, 0.f, 0.f, 0.f};
#pragma unroll
            for (int c = 0; c < 2; ++c) {
                ng = mfma1(H2f[c], BG[c], ng);
                nb = mfma1(H1f[c], B0[c], nb);
            }
            P1 = ng + nb;

            // fc on all waves (balanced); only wave 0 p<2 stores
            f32x4 fcC = {0.f, 0.f, 0.f, 0.f};
#pragma unroll
            for (int c = 0; c < 2; ++c)
                fcC = mfma1(H2f[c], BF[c], fcC);
            if (wv == 0 && p < 2) {
#pragma unroll
                for (int r = 0; r < 4; ++r)
                    predbuf[((4 * q + r) * kTP + t) * 2 + p] = fcC[r] + fbp;
            }
        }
    }

    // flush preds: only the kM REAL rows; block covers out[r0*kTP*2 .. (r0+8)*kTP*2)
    __syncthreads();
    {
        float4* dst = reinterpret_cast<float4*>(out + r0 * (kTP * 2));
        const float4* src = reinterpret_cast<const float4*>(predbuf);
        for (int i = tid; i < kM * kTP * 2 / 4; i += 256)
            dst[i] = src[i];
    }
}

extern "C" void kernel_launch(void* const* d_in, const int* in_sizes, int n_in,
                              void* d_out, int out_size, void* d_ws, size_t ws_size,
                              hipStream_t stream) {
    const float* x     = (const float*)d_in[0];
    const float* eWih0 = (const float*)d_in[1];
    const float* eWhh0 = (const float*)d_in[2];
    const float* ebih0 = (const float*)d_in[3];
    const float* ebhh0 = (const float*)d_in[4];
    const float* eWih1 = (const float*)d_in[5];
    const float* eWhh1 = (const float*)d_in[6];
    const float* ebih1 = (const float*)d_in[7];
    const float* ebhh1 = (const float*)d_in[8];
    const float* dWih0 = (const float*)d_in[9];
    const float* dWhh0 = (const float*)d_in[10];
    const float* dbih0 = (const float*)d_in[11];
    const float* dbhh0 = (const float*)d_in[12];
    const float* dWih1 = (const float*)d_in[13];
    const float* dWhh1 = (const float*)d_in[14];
    const float* dbih1 = (const float*)d_in[15];
    const float* dbhh1 = (const float*)d_in[16];
    const float* fcW   = (const float*)d_in[17];
    const float* fcb   = (const float*)d_in[18];
    float* out = (float*)d_out;

    dim3 grid(kB / kM);   // 1024 blocks x 4 waves: 4 independent blocks per SIMD
    dim3 block(256);
    traj_rnn_kernel<<<grid, block, 0, stream>>>(
        x, eWih0, eWhh0, ebih0, ebhh0, eWih1, eWhh1, ebih1, ebhh1,
        dWih0, dWhh0, dbih0, dbhh0, dWih1, dWhh1, dbih1, dbhh1,
        fcW, fcb, out);
}